// Round 8
// baseline (247.539 us; speedup 1.0000x reference)
//
#include <hip/hip_runtime.h>

// ---------------------------------------------------------------------------
// MHA: out = (softmax(split(XqWq^T+bq) @ split(XkWk^T+bk)^T / 8) @ split(XvWv^T+bv)) @ Wo^T + bo
// B=2, S=2048, D=1024, H=16, Dk=64. fp32 I/O; bf16 MFMA compute.
// R8: X-convert fused into qkv (fp32 A reg-staged, cvt_pk, T14 issue-early/
//     write-late); weights-only mini-convert; gemm_o 2-buf counted vmcnt;
//     both GEMMs 64 KB LDS -> 2 blocks/CU. Attn unchanged (control).
// ---------------------------------------------------------------------------

typedef short bf16x8 __attribute__((ext_vector_type(8)));
typedef float f32x4 __attribute__((ext_vector_type(4)));

#define D_MODEL 1024
#define NHEAD 16
#define DK 64
#define BB 2
#define SS 2048
#define MROWS (BB * SS) /* 4096 */
#define C1 0.18033688011112042f /* (1/8)*log2(e) */

__device__ __forceinline__ unsigned short f2bf(float f) {
  unsigned u = __builtin_bit_cast(unsigned, f);
  u += 0x7fffu + ((u >> 16) & 1u);  // RNE
  return (unsigned short)(u >> 16);
}
__device__ __forceinline__ unsigned pack2(float a, float b) {
  return (unsigned)f2bf(a) | ((unsigned)f2bf(b) << 16);
}
__device__ __forceinline__ unsigned cvtpk(float lo, float hi) {
  unsigned r;
  asm("v_cvt_pk_bf16_f32 %0, %1, %2" : "=v"(r) : "v"(lo), "v"(hi));
  return r;
}
__device__ __forceinline__ float max3f(float a, float b, float c) {
  float d;
  asm("v_max3_f32 %0, %1, %2, %3" : "=v"(d) : "v"(a), "v"(b), "v"(c));
  return d;
}

typedef __attribute__((address_space(3))) unsigned int as3u;
typedef const __attribute__((address_space(1))) unsigned int as1u;
__device__ __forceinline__ void gload16(void* lds, const void* g) {
  __builtin_amdgcn_global_load_lds((as1u*)g, (as3u*)lds, 16, 0, 0);
}
__device__ __forceinline__ void waitv8()  { asm volatile("s_waitcnt vmcnt(8)"  ::: "memory"); }
__device__ __forceinline__ void waitv4()  { asm volatile("s_waitcnt vmcnt(4)"  ::: "memory"); }
__device__ __forceinline__ void waitv0()  { asm volatile("s_waitcnt vmcnt(0)"  ::: "memory"); }

// ---------------------------------------------------------------------------
// Weights-only fp32 -> bf16 conversion (24 MB traffic)
// ---------------------------------------------------------------------------
struct CvtArgs {
  const float* s[4];
  unsigned short* d[4];
};

__global__ __launch_bounds__(256) void convert_w(CvtArgs a) {
  const int slot = blockIdx.y;
  const float* __restrict__ s = a.s[slot];
  unsigned short* __restrict__ d = a.d[slot];
  const int n8 = (D_MODEL * D_MODEL) / 8;
  for (int i = blockIdx.x * 256 + threadIdx.x; i < n8; i += gridDim.x * 256) {
    const size_t off = (size_t)i * 8;
    const float4 v0 = *(const float4*)&s[off];
    const float4 v1 = *(const float4*)&s[off + 4];
    uint4 p;
    p.x = pack2(v0.x, v0.y); p.y = pack2(v0.z, v0.w);
    p.z = pack2(v1.x, v1.y); p.w = pack2(v1.z, v1.w);
    *(uint4*)&d[off] = p;
  }
}

// ---------------------------------------------------------------------------
// QKV GEMM: C = X(fp32) * W(bf16)^T + bias. 128x128 tile, BK=64, 2-buf (64 KB).
// A staged via reg (fp32 load -> cvt_pk -> swizzled ds_write_b128), W via
// global_load_lds (pre-swizzled source). T14: next tile's loads issued BEFORE
// compute; vmcnt(0)+ds_write after. One __syncthreads per K-step.
// MODE 0: bf16 C (scaled). MODE 2: C^T -> vT[b*1024+col][s].
// ---------------------------------------------------------------------------
template <int MODE>
__device__ __forceinline__ void gemm_qkv_core(unsigned short* smem,
                                              const float* __restrict__ A,
                                              const unsigned short* __restrict__ B,
                                              const float* __restrict__ bias,
                                              float scale, int bm, int nb,
                                              unsigned short* __restrict__ Cb) {
  const int BUF = 2 * 128 * 64;  // elems per buffer (As half + Bs half)
  const int tid = threadIdx.x;
  const int lane = tid & 63, w = tid >> 6;
  const int wm = w >> 1, wn = w & 1;
  const int l15 = lane & 15, l4 = lane >> 4;

  // W staging: 4 gload16; LDS slot g holds global group g^(row&7).
  auto stageW = [&](unsigned short* Bs, int k0) {
#pragma unroll
    for (int i = 0; i < 4; ++i) {
      const int flat = i * 256 + tid;
      const int row = flat >> 3, g = flat & 7;
      gload16(&Bs[flat * 8], &B[(size_t)(nb * 128 + row) * D_MODEL + k0 + ((g ^ (row & 7)) << 3)]);
    }
  };
  // A load: 8 float4 into regs (linear group g read; swizzle applied on write)
  auto loadA = [&](float4 (&ar)[4][2], int k0) {
#pragma unroll
    for (int i = 0; i < 4; ++i) {
      const int flat = i * 256 + tid;
      const int row = flat >> 3, g = flat & 7;
      const float* src = &A[(size_t)(bm * 128 + row) * D_MODEL + k0 + g * 8];
      ar[i][0] = *(const float4*)src;
      ar[i][1] = *(const float4*)(src + 4);
    }
  };
  auto writeA = [&](unsigned short* As, float4 (&ar)[4][2]) {
#pragma unroll
    for (int i = 0; i < 4; ++i) {
      const int flat = i * 256 + tid;
      const int row = flat >> 3, g = flat & 7;
      uint4 p;
      p.x = cvtpk(ar[i][0].x, ar[i][0].y); p.y = cvtpk(ar[i][0].z, ar[i][0].w);
      p.z = cvtpk(ar[i][1].x, ar[i][1].y); p.w = cvtpk(ar[i][1].z, ar[i][1].w);
      *(uint4*)&As[row * 64 + ((g ^ (row & 7)) << 3)] = p;
    }
  };

  f32x4 acc[4][4];
#pragma unroll
  for (int m = 0; m < 4; ++m)
#pragma unroll
    for (int n = 0; n < 4; ++n) acc[m][n] = (f32x4){0.f, 0.f, 0.f, 0.f};

  float4 ar[4][2];
  // prologue: tile 0
  stageW(smem + 128 * 64, 0);
  loadA(ar, 0);
  waitv0();
  writeA(smem, ar);
  __syncthreads();

  int cur = 0;
#pragma unroll 1
  for (int t = 0; t < 16; ++t) {
    unsigned short* As = smem + cur * BUF;
    unsigned short* Bs = As + 128 * 64;
    unsigned short* Asn = smem + (cur ^ 1) * BUF;
    const bool more = (t + 1 < 16);
    if (more) {                     // issue-early (T14): hides under compute
      stageW(Asn + 128 * 64, (t + 1) * 64);
      loadA(ar, (t + 1) * 64);
    }
#pragma unroll
    for (int kk = 0; kk < 2; ++kk) {
      bf16x8 af[4], bf[4];
#pragma unroll
      for (int m = 0; m < 4; ++m) {
        const int r = wm * 64 + m * 16 + l15;
        af[m] = *(const bf16x8*)&As[r * 64 + (((kk * 4 + l4) ^ (r & 7)) << 3)];
      }
#pragma unroll
      for (int n = 0; n < 4; ++n) {
        const int r = wn * 64 + n * 16 + l15;
        bf[n] = *(const bf16x8*)&Bs[r * 64 + (((kk * 4 + l4) ^ (r & 7)) << 3)];
      }
#pragma unroll
      for (int m = 0; m < 4; ++m)
#pragma unroll
        for (int n = 0; n < 4; ++n)
          acc[m][n] = __builtin_amdgcn_mfma_f32_16x16x32_bf16(af[m], bf[n], acc[m][n], 0, 0, 0);
    }
    if (more) {
      waitv0();                     // A regs + W gload landed (issued ~compute ago)
      writeA(Asn, ar);              // write-late into the idle buffer
    }
    __syncthreads();                // drains lgkm; publishes buf^1 for t+1
    cur ^= 1;
  }

  if (MODE == 0) {
#pragma unroll
    for (int m = 0; m < 4; ++m)
#pragma unroll
      for (int n = 0; n < 4; ++n) {
        const int col = nb * 128 + wn * 64 + n * 16 + l15;
        const float bv = bias[col];
#pragma unroll
        for (int r = 0; r < 4; ++r) {
          const int row = bm * 128 + wm * 64 + m * 16 + l4 * 4 + r;
          Cb[(size_t)row * D_MODEL + col] = f2bf((acc[m][n][r] + bv) * scale);
        }
      }
  } else {
    // C^T through LDS: T[cl][rl], pitch 256 B, group swizzle (rl>>3)^(cl&7)
    unsigned short* T = smem;
#pragma unroll
    for (int m = 0; m < 4; ++m)
#pragma unroll
      for (int n = 0; n < 4; ++n) {
        const int cl = wn * 64 + n * 16 + l15;
        const float bv = bias[nb * 128 + cl];
#pragma unroll
        for (int r = 0; r < 4; ++r) {
          const int rl = wm * 64 + m * 16 + l4 * 4 + r;
          const int byte = cl * 256 + ((((rl >> 3) ^ (cl & 7))) << 4) + ((rl & 7) << 1);
          *(unsigned short*)((char*)T + byte) = f2bf(acc[m][n][r] + bv);
        }
      }
    __syncthreads();
#pragma unroll
    for (int c = 0; c < 8; ++c) {
      const int chunk = c * 256 + tid;  // 0..2047
      const int cl = chunk >> 4, rl0 = (chunk & 15) * 8;
      const int byte = cl * 256 + (((rl0 >> 3) ^ (cl & 7)) << 4);
      const uint4 val = *(const uint4*)((const char*)T + byte);
      const int gcol = nb * 128 + cl;
      const int bb = (bm * 128) >> 11;
      const int s = ((bm * 128) & 2047) + rl0;
      *(uint4*)&Cb[(size_t)(bb * 1024 + gcol) * SS + s] = val;
    }
  }
}

// Fused QKV: 768 blocks, XCD-chunked swizzle (768 % 8 == 0 -> bijective).
__global__ __launch_bounds__(256, 2) void gemm_qkv(
    const float* __restrict__ Qin, const float* __restrict__ Kin,
    const float* __restrict__ Vin,
    const unsigned short* __restrict__ Wq, const float* __restrict__ bq,
    const unsigned short* __restrict__ Wk, const float* __restrict__ bk,
    const unsigned short* __restrict__ Wv, const float* __restrict__ bv,
    unsigned short* __restrict__ q, unsigned short* __restrict__ k,
    unsigned short* __restrict__ vT) {
  __shared__ __align__(16) unsigned short smem[2 * 2 * 128 * 64];  // 64 KB
  const int lin = blockIdx.x + 24 * blockIdx.y;  // 0..767
  const int swz = (lin % 8) * 96 + lin / 8;
  const int bn = swz % 24, bm = swz / 24;
  const int z = bn >> 3, nb = bn & 7;
  if (z == 0) {
    gemm_qkv_core<0>(smem, Qin, Wq, bq, C1, bm, nb, q);  // q pre-scaled
  } else if (z == 1) {
    gemm_qkv_core<0>(smem, Kin, Wk, bk, 1.0f, bm, nb, k);
  } else {
    gemm_qkv_core<2>(smem, Vin, Wv, bv, 1.0f, bm, nb, vT);
  }
}

// ---------------------------------------------------------------------------
// Output GEMM: C(f32) = A(bf16) * W(bf16)^T + bias. 128x128, BK=64, 2-buf,
// counted vmcnt(8) (per-wave wait, then barrier: all waves' tile-t complete).
// ---------------------------------------------------------------------------
__global__ __launch_bounds__(256, 2) void gemm_o(const unsigned short* __restrict__ A,
                                                 const unsigned short* __restrict__ W,
                                                 const float* __restrict__ bi,
                                                 float* __restrict__ out) {
  __shared__ __align__(16) unsigned short smem[2 * 2 * 128 * 64];  // 64 KB
  const int BUF = 2 * 128 * 64;
  const int lin = blockIdx.x + 8 * blockIdx.y;  // 0..255
  const int swz = (lin % 8) * 32 + lin / 8;
  const int nb = swz % 8, bm = swz / 8;
  const int tid = threadIdx.x;
  const int lane = tid & 63, w = tid >> 6;
  const int wm = w >> 1, wn = w & 1;
  const int l15 = lane & 15, l4 = lane >> 4;

  auto stage = [&](unsigned short* dst, int k0) {  // 8 gload16
    unsigned short* As = dst;
    unsigned short* Bs = dst + 128 * 64;
#pragma unroll
    for (int i = 0; i < 4; ++i) {
      const int flat = i * 256 + tid;
      const int row = flat >> 3, g = flat & 7;
      const int gs = (g ^ (row & 7)) << 3;
      gload16(&As[flat * 8], &A[(size_t)(bm * 128 + row) * D_MODEL + k0 + gs]);
    }
#pragma unroll
    for (int i = 0; i < 4; ++i) {
      const int flat = i * 256 + tid;
      const int row = flat >> 3, g = flat & 7;
      const int gs = (g ^ (row & 7)) << 3;
      gload16(&Bs[flat * 8], &W[(size_t)(nb * 128 + row) * D_MODEL + k0 + gs]);
    }
  };

  f32x4 acc[4][4];
#pragma unroll
  for (int m = 0; m < 4; ++m)
#pragma unroll
    for (int n = 0; n < 4; ++n) acc[m][n] = (f32x4){0.f, 0.f, 0.f, 0.f};

  stage(smem, 0);
  int cur = 0;
#pragma unroll 1
  for (int t = 0; t < 16; ++t) {
    if (t + 1 < 16) stage(smem + (cur ^ 1) * BUF, (t + 1) * 64);
    if (t + 1 < 16) waitv8();   // tile t's 8 done; t+1's 8 stay in flight
    else waitv0();
    __builtin_amdgcn_s_barrier();
    unsigned short* As = smem + cur * BUF;
    unsigned short* Bs = As + 128 * 64;
#pragma unroll
    for (int kk = 0; kk < 2; ++kk) {
      bf16x8 af[4], bf[4];
#pragma unroll
      for (int m = 0; m < 4; ++m) {
        const int r = wm * 64 + m * 16 + l15;
        af[m] = *(const bf16x8*)&As[r * 64 + (((kk * 4 + l4) ^ (r & 7)) << 3)];
      }
#pragma unroll
      for (int n = 0; n < 4; ++n) {
        const int r = wn * 64 + n * 16 + l15;
        bf[n] = *(const bf16x8*)&Bs[r * 64 + (((kk * 4 + l4) ^ (r & 7)) << 3)];
      }
#pragma unroll
      for (int m = 0; m < 4; ++m)
#pragma unroll
        for (int n = 0; n < 4; ++n)
          acc[m][n] = __builtin_amdgcn_mfma_f32_16x16x32_bf16(af[m], bf[n], acc[m][n], 0, 0, 0);
    }
    __builtin_amdgcn_s_barrier();  // all reads of buf done before overwrite
    cur ^= 1;
  }

#pragma unroll
  for (int m = 0; m < 4; ++m)
#pragma unroll
    for (int n = 0; n < 4; ++n) {
      const int col = nb * 128 + wn * 64 + n * 16 + l15;
      const float bv = bi[col];
#pragma unroll
      for (int r = 0; r < 4; ++r) {
        const int row = bm * 128 + wm * 64 + m * 16 + l4 * 4 + r;
        out[(size_t)row * D_MODEL + col] = acc[m][n][r] + bv;
      }
    }
}

// ---------------------------------------------------------------------------
// Flash attention (unchanged from R7): swapped-QK^T, in-reg softmax, 3-ring
// K/V staging counted vmcnt, ones-column MFMA row-sum, defer-max THR=8.
// ---------------------------------------------------------------------------
__global__ __launch_bounds__(256, 2) void attn_kernel(
    const unsigned short* __restrict__ Qp, const unsigned short* __restrict__ Kp,
    const unsigned short* __restrict__ vTp, unsigned short* __restrict__ Op) {
  __shared__ __align__(16) unsigned short Kt[3][64 * 64];
  __shared__ __align__(16) unsigned short Vt[3][64 * 64];  // [d][s]
  __shared__ __align__(16) unsigned short Pt[4][32 * 64];  // per-wave P
  const int tid = threadIdx.x;
  const int lane = tid & 63, w = tid >> 6;
  const int l15 = lane & 15, l4 = lane >> 4;
  const int bh = blockIdx.x;  // 0..31
  const int b = bh >> 4, h = bh & 15;
  const int qb = blockIdx.y;  // 0..15
  const size_t baseQ = (size_t)b * SS * D_MODEL + (size_t)h * DK;
  const size_t baseV = (size_t)(b * 1024 + h * 64) * SS;

  bf16x8 aq[2][2];
#pragma unroll
  for (int m = 0; m < 2; ++m) {
    const int qrow = qb * 128 + w * 32 + m * 16 + l15;
#pragma unroll
    for (int kk = 0; kk < 2; ++kk)
      aq[m][kk] = *(const bf16x8*)&Qp[baseQ + (size_t)qrow * D_MODEL + kk * 32 + l4 * 8];
  }

  const bf16x8 vone = {0x3F80, 0x3F80, 0x3F80, 0x3F80, 0x3F80, 0x3F80, 0x3F80, 0x3F80};

  float rm[2] = {-1e30f, -1e30f};
  f32x4 acc[2][5];
#pragma unroll
  for (int m = 0; m < 2; ++m)
#pragma unroll
    for (int d = 0; d < 5; ++d) acc[m][d] = (f32x4){0.f, 0.f, 0.f, 0.f};

  auto stage = [&](int buf, int kt) {
#pragma unroll
    for (int i = 0; i < 2; ++i) {
      const int flat = (w * 2 + i) * 64 + lane;
      const int row = flat >> 3, g = flat & 7;
      gload16(&Kt[buf][flat * 8],
              &Kp[baseQ + (size_t)(kt * 64 + row) * D_MODEL + ((g ^ (row & 7)) << 3)]);
    }
#pragma unroll
    for (int i = 0; i < 2; ++i) {
      const int flat = (w * 2 + i) * 64 + lane;
      const int row = flat >> 3, g = flat & 7;
      gload16(&Vt[buf][flat * 8],
              &vTp[baseV + (size_t)row * SS + kt * 64 + ((g ^ (row & 7)) << 3)]);
    }
  };

  stage(0, 0);
  stage(1, 1);
#pragma unroll 1
  for (int kt = 0; kt < SS / 64; ++kt) {
    const int bs = kt % 3;
    if (kt < SS / 64 - 2) {
      int bst = bs + 2; if (bst >= 3) bst -= 3;
      stage(bst, kt + 2);
    }
    if (kt < SS / 64 - 2) waitv8();
    else if (kt == SS / 64 - 2) waitv4();
    else waitv0();
    __builtin_amdgcn_s_barrier();

    f32x4 st[2][4];
#pragma unroll
    for (int m = 0; m < 2; ++m)
#pragma unroll
      for (int n = 0; n < 4; ++n) st[m][n] = (f32x4){0.f, 0.f, 0.f, 0.f};
#pragma unroll
    for (int kk = 0; kk < 2; ++kk) {
      bf16x8 kf[4];
#pragma unroll
      for (int n = 0; n < 4; ++n) {
        const int r = n * 16 + l15;
        kf[n] = *(const bf16x8*)&Kt[bs][r * 64 + (((kk * 4 + l4) ^ (r & 7)) << 3)];
      }
#pragma unroll
      for (int m = 0; m < 2; ++m)
#pragma unroll
        for (int n = 0; n < 4; ++n)
          st[m][n] = __builtin_amdgcn_mfma_f32_16x16x32_bf16(kf[n], aq[m][kk], st[m][n], 0, 0, 0);
    }

    float mx[2];
#pragma unroll
    for (int m = 0; m < 2; ++m) {
      const float a0 = max3f(st[m][0][0], st[m][0][1], st[m][0][2]);
      const float a1 = max3f(st[m][0][3], st[m][1][0], st[m][1][1]);
      const float a2 = max3f(st[m][1][2], st[m][1][3], st[m][2][0]);
      const float a3 = max3f(st[m][2][1], st[m][2][2], st[m][2][3]);
      const float a4 = max3f(st[m][3][0], st[m][3][1], st[m][3][2]);
      float v = fmaxf(max3f(a0, a1, a2), max3f(a3, a4, st[m][3][3]));
      v = fmaxf(v, __shfl_xor(v, 16));
      v = fmaxf(v, __shfl_xor(v, 32));
      mx[m] = v;
    }
    if (__any((mx[0] > rm[0] + 8.f) | (mx[1] > rm[1] + 8.f))) {
#pragma unroll
      for (int m = 0; m < 2; ++m) {
        const float nm = fmaxf(rm[m], mx[m]);
        const float alpha = exp2f(rm[m] - nm);
        rm[m] = nm;
#pragma unroll
        for (int r = 0; r < 4; ++r) {
          const float ar = __shfl(alpha, l4 * 4 + r);
#pragma unroll
          for (int d = 0; d < 5; ++d) acc[m][d][r] *= ar;
        }
      }
    }
#pragma unroll
    for (int m = 0; m < 2; ++m)
#pragma unroll
      for (int n = 0; n < 4; ++n)
#pragma unroll
        for (int r = 0; r < 4; ++r) st[m][n][r] = exp2f(st[m][n][r] - rm[m]);

#pragma unroll
    for (int m = 0; m < 2; ++m)
#pragma unroll
      for (int n = 0; n < 4; ++n)
#pragma unroll
        for (int c = 0; c < 2; ++c) {
          const int col = n * 16 + l4 * 4 + 2 * c;
          const int row = m * 16 + l15;
          const int sw = (((col >> 3) ^ (row & 7)) << 3) + (col & 7);
          *(unsigned*)&Pt[w][row * 64 + sw] = cvtpk(st[m][n][2 * c], st[m][n][2 * c + 1]);
        }

#pragma unroll
    for (int kk = 0; kk < 2; ++kk) {
      bf16x8 ap[2], vf[4];
#pragma unroll
      for (int m = 0; m < 2; ++m) {
        const int r = m * 16 + l15;
        ap[m] = *(const bf16x8*)&Pt[w][r * 64 + (((kk * 4 + l4) ^ (r & 7)) << 3)];
      }
#pragma unroll
      for (int d = 0; d < 4; ++d) {
        const int r = d * 16 + l15;
        vf[d] = *(const bf16x8*)&Vt[bs][r * 64 + (((kk * 4 + l4) ^ (r & 7)) << 3)];
      }
#pragma unroll
      for (int m = 0; m < 2; ++m) {
#pragma unroll
        for (int d = 0; d < 4; ++d)
          acc[m][d] = __builtin_amdgcn_mfma_f32_16x16x32_bf16(ap[m], vf[d], acc[m][d], 0, 0, 0);
        acc[m][4] = __builtin_amdgcn_mfma_f32_16x16x32_bf16(ap[m], vone, acc[m][4], 0, 0, 0);
      }
    }

    __builtin_amdgcn_s_barrier();
  }

#pragma unroll
  for (int m = 0; m < 2; ++m) {
    float inv[4];
#pragma unroll
    for (int r = 0; r < 4; ++r) inv[r] = 1.0f / acc[m][4][r];
#pragma unroll
    for (int d = 0; d < 4; ++d)
#pragma unroll
      for (int r = 0; r < 4; ++r) {
        const int orow = qb * 128 + w * 32 + m * 16 + l4 * 4 + r;
        Op[baseQ + (size_t)orow * D_MODEL + d * 16 + l15] = f2bf(acc[m][d][r] * inv[r]);
      }
  }
}

extern "C" void kernel_launch(void* const* d_in, const int* in_sizes, int n_in,
                              void* d_out, int out_size, void* d_ws, size_t ws_size,
                              hipStream_t stream) {
  const float* Qin = (const float*)d_in[0];
  const float* Kin = (const float*)d_in[1];
  const float* Vin = (const float*)d_in[2];
  const float* Wq = (const float*)d_in[3];
  const float* bq = (const float*)d_in[4];
  const float* Wk = (const float*)d_in[5];
  const float* bk = (const float*)d_in[6];
  const float* Wv = (const float*)d_in[7];
  const float* bv = (const float*)d_in[8];
  const float* Wo = (const float*)d_in[9];
  const float* bo = (const float*)d_in[10];
  float* out = (float*)d_out;

  const size_t NX = (size_t)MROWS * D_MODEL;
  const size_t NW = (size_t)D_MODEL * D_MODEL;
  unsigned short* ws = (unsigned short*)d_ws;
  unsigned short* q  = ws;            // projected q (bf16, pre-scaled by C1)
  unsigned short* k  = ws + NX;       // projected k
  unsigned short* vT = ws + 2 * NX;   // projected v^T [b*1024+col][s]
  unsigned short* ao = ws + 3 * NX;   // attention output (merged heads, bf16)
  unsigned short* wq = ws + 4 * NX;
  unsigned short* wk = wq + NW;
  unsigned short* wv = wk + NW;
  unsigned short* wo = wv + NW;       // total 40 MB

  CvtArgs ca;
  ca.s[0] = Wq; ca.d[0] = wq;
  ca.s[1] = Wk; ca.d[1] = wk;
  ca.s[2] = Wv; ca.d[2] = wv;
  ca.s[3] = Wo; ca.d[3] = wo;
  convert_w<<<dim3(128, 4), 256, 0, stream>>>(ca);

  gemm_qkv<<<dim3(24, 32), 256, 0, stream>>>(
      Qin, Kin, Vin, wq, bq, wk, bk, wv, bv, q, k, vT);
  attn_kernel<<<dim3(BB * NHEAD, SS / 128), 256, 0, stream>>>(q, k, vT, ao);
  gemm_o<<<dim3(8, 32), 256, 0, stream>>>(ao, wo, bo, out);
}